// Round 1
// baseline (824.467 us; speedup 1.0000x reference)
//
#include <hip/hip_runtime.h>
#include <stdint.h>

typedef unsigned short u16;
typedef unsigned int u32;
typedef __attribute__((ext_vector_type(8))) short short8;
typedef __attribute__((ext_vector_type(4))) float f32x4;

#define BATCH 16
#define CCH   512
#define NPIX  1024
#define NGRP  8
#define CPG   64
#define NHEAD 4
#define HDIM  128

__device__ __forceinline__ u16 f2bf(float f) {
  union { float f; u32 u; } v; v.f = f;
  u32 u = v.u;
  u32 r = (u + 0x7FFFu + ((u >> 16) & 1u)) >> 16;
  return (u16)r;
}

// ---------------- GroupNorm stats: one block per (b,g) ----------------
__global__ void gn_stats_k(const float* __restrict__ x, float* __restrict__ stats) {
  int bg = blockIdx.x;  // b*8+g ; channels of a group are contiguous
  const float* p = x + (size_t)bg * (CPG * NPIX);
  float s = 0.f, ss = 0.f;
  for (int i = threadIdx.x; i < (CPG * NPIX) / 4; i += 256) {
    float4 v = reinterpret_cast<const float4*>(p)[i];
    s  += v.x + v.y + v.z + v.w;
    ss += v.x*v.x + v.y*v.y + v.z*v.z + v.w*v.w;
  }
  for (int o = 32; o > 0; o >>= 1) { s += __shfl_down(s, o); ss += __shfl_down(ss, o); }
  __shared__ float sh[8];
  int wid = threadIdx.x >> 6;
  if ((threadIdx.x & 63) == 0) { sh[wid*2] = s; sh[wid*2+1] = ss; }
  __syncthreads();
  if (threadIdx.x == 0) {
    float ts  = sh[0]+sh[2]+sh[4]+sh[6];
    float tss = sh[1]+sh[3]+sh[5]+sh[7];
    const float inv = 1.f / (float)(CPG*NPIX);
    float mean = ts * inv;
    float var  = tss * inv - mean*mean;
    stats[bg*2]   = mean;
    stats[bg*2+1] = rsqrtf(var + 1e-5f);
  }
}

// ---------------- GroupNorm apply -> bf16 xn ----------------
__global__ void gn_apply_k(const float* __restrict__ x, const float* __restrict__ gamma,
                           const float* __restrict__ beta, const float* __restrict__ stats,
                           u16* __restrict__ xn) {
  int t = blockIdx.x * 256 + threadIdx.x;      // one float4 per thread
  int c = (t >> 8) & (CCH - 1);                // 256 vec4 per row of 1024
  int b = t >> 17;
  int g = c >> 6;
  float mean = stats[(b*NGRP + g)*2];
  float rstd = stats[(b*NGRP + g)*2 + 1];
  float ga = gamma[c] * rstd;
  float be = beta[c] - mean * ga;
  float4 v = reinterpret_cast<const float4*>(x)[t];
  u16 o0 = f2bf(v.x*ga + be), o1 = f2bf(v.y*ga + be);
  u16 o2 = f2bf(v.z*ga + be), o3 = f2bf(v.w*ga + be);
  u32 lo = (u32)o0 | ((u32)o1 << 16);
  u32 hi = (u32)o2 | ((u32)o3 << 16);
  reinterpret_cast<uint2*>(xn)[t] = make_uint2(lo, hi);
}

// ---------------- fp32 -> bf16 weight conversion ----------------
__global__ void f2bf_vec_k(const float* __restrict__ src, u16* __restrict__ dst, int n4) {
  int i = blockIdx.x * 256 + threadIdx.x;
  if (i >= n4) return;
  float4 v = reinterpret_cast<const float4*>(src)[i];
  u32 lo = (u32)f2bf(v.x) | ((u32)f2bf(v.y) << 16);
  u32 hi = (u32)f2bf(v.z) | ((u32)f2bf(v.w) << 16);
  reinterpret_cast<uint2*>(dst)[i] = make_uint2(lo, hi);
}

// ---------------- GEMM: C[b][m][n] = sum_k W[m][k] * Bm[b][k][n] ----------------
// W: M x 512 row-major bf16.  Bm: 16 x 512 x 1024 bf16.
// PROJ=false: write bf16 C.  PROJ=true: outF = xres + C + bias[m] (fp32).
template <bool PROJ>
__global__ __launch_bounds__(256) void gemm_k512(const u16* __restrict__ W,
                                                 const u16* __restrict__ Bm,
                                                 u16* __restrict__ outBf,
                                                 const float* __restrict__ xres,
                                                 const float* __restrict__ bias,
                                                 float* __restrict__ outF) {
  const int b  = blockIdx.z;
  const int m0 = blockIdx.y * 64;
  const int n0 = blockIdx.x * 64;
  const int M  = PROJ ? 512 : 1536;
  const u16* Bp = Bm + (size_t)b * CCH * NPIX;

  __shared__ u16 As[64][40];    // [m][k], padded
  __shared__ u16 BsT[64][40];   // [n][k], transposed, padded

  const int t    = threadIdx.x;
  const int lane = t & 63, wid = t >> 6;
  const int lr = lane & 15, lh = lane >> 4;
  const int wm = (wid >> 1) * 32, wn = (wid & 1) * 32;

  f32x4 acc[2][2] = {};

  const int ar = t >> 2, ac = (t & 3) * 8;   // A: 64 rows x 32 k
  const int br = t >> 3, bc = (t & 7) * 8;   // B: 32 k x 64 n

  for (int kt = 0; kt < 16; ++kt) {
    const int k0 = kt * 32;
    // stage A (coalesced 16B)
    *reinterpret_cast<uint4*>(&As[ar][ac]) =
        *reinterpret_cast<const uint4*>(&W[(size_t)(m0 + ar) * CCH + k0 + ac]);
    // stage B transposed (coalesced 16B load, scalar transpose store)
    uint4 gv = *reinterpret_cast<const uint4*>(&Bp[(size_t)(k0 + br) * NPIX + n0 + bc]);
    u16 e[8];
    *reinterpret_cast<uint4*>(e) = gv;
    #pragma unroll
    for (int j = 0; j < 8; ++j) BsT[bc + j][br] = e[j];
    __syncthreads();

    short8 af[2], bfr[2];
    #pragma unroll
    for (int f = 0; f < 2; ++f)
      af[f] = *reinterpret_cast<const short8*>(&As[wm + f*16 + lr][lh*8]);
    #pragma unroll
    for (int f = 0; f < 2; ++f)
      bfr[f] = *reinterpret_cast<const short8*>(&BsT[wn + f*16 + lr][lh*8]);

    #pragma unroll
    for (int fm = 0; fm < 2; ++fm)
      #pragma unroll
      for (int fn = 0; fn < 2; ++fn)
        acc[fm][fn] = __builtin_amdgcn_mfma_f32_16x16x32_bf16(af[fm], bfr[fn], acc[fm][fn], 0, 0, 0);
    __syncthreads();
  }

  #pragma unroll
  for (int fm = 0; fm < 2; ++fm)
    #pragma unroll
    for (int fn = 0; fn < 2; ++fn)
      #pragma unroll
      for (int r = 0; r < 4; ++r) {
        int m = m0 + wm + fm*16 + lh*4 + r;
        int n = n0 + wn + fn*16 + lr;
        size_t off = ((size_t)b * M + m) * NPIX + n;
        float v = acc[fm][fn][r];
        if (PROJ) {
          outF[off] = xres[off] + v + bias[m];
        } else {
          outBf[off] = f2bf(v);
        }
      }
}

// ---------------- Flash attention: 1 wave per (b, h, 16 q rows) ----------------
__global__ void attn_k(const u16* __restrict__ qkv, u16* __restrict__ out) {
  const int qt = blockIdx.x;         // 64 tiles of 16 q rows
  const int h  = blockIdx.y;
  const int b  = blockIdx.z;
  const size_t headoff = ((size_t)b * 3 * CCH + h * HDIM) * NPIX;
  const u16* Q = qkv + headoff;
  const u16* K = Q + (size_t)CCH * NPIX;
  const u16* V = K + (size_t)CCH * NPIX;

  const int lane = threadIdx.x;
  const int lr = lane & 15, lh = lane >> 4;

  __shared__ u16 Ps[32][20];

  // Q fragments: lane holds Q[c-slot][q = qt*16+lr]
  short8 qf[4];
  #pragma unroll
  for (int ct = 0; ct < 4; ++ct) {
    short8 v;
    #pragma unroll
    for (int j = 0; j < 8; ++j)
      v[j] = (short)Q[(size_t)(ct*32 + lh*8 + j) * NPIX + qt*16 + lr];
    qf[ct] = v;
  }

  f32x4 of[8] = {};
  float m_run = -1e30f, l_run = 0.f;
  const float scale = 0.08838834764831845f;  // 1/sqrt(128)

  for (int kv0 = 0; kv0 < NPIX; kv0 += 32) {
    // S tile: mfma(A=K, B=Q) -> reg r holds S[j = kv0+t2*16+lh*4+r][i = qt*16+lr]
    f32x4 s[2] = {};
    #pragma unroll
    for (int t2 = 0; t2 < 2; ++t2)
      #pragma unroll
      for (int ct = 0; ct < 4; ++ct) {
        short8 kf;
        #pragma unroll
        for (int j = 0; j < 8; ++j)
          kf[j] = (short)K[(size_t)(ct*32 + lh*8 + j) * NPIX + kv0 + t2*16 + lr];
        s[t2] = __builtin_amdgcn_mfma_f32_16x16x32_bf16(kf, qf[ct], s[t2], 0, 0, 0);
      }

    float sv[8];
    float tm = -1e30f;
    #pragma unroll
    for (int t2 = 0; t2 < 2; ++t2)
      #pragma unroll
      for (int r = 0; r < 4; ++r) {
        float xv = s[t2][r] * scale;
        sv[t2*4 + r] = xv;
        tm = fmaxf(tm, xv);
      }
    tm = fmaxf(tm, __shfl_xor(tm, 16));
    tm = fmaxf(tm, __shfl_xor(tm, 32));
    float m_new = fmaxf(m_run, tm);
    float corr = __expf(m_run - m_new);

    float psum = 0.f;
    u16 pb[8];
    #pragma unroll
    for (int i2 = 0; i2 < 8; ++i2) {
      float p = __expf(sv[i2] - m_new);
      psum += p;
      pb[i2] = f2bf(p);
    }
    psum += __shfl_xor(psum, 16);
    psum += __shfl_xor(psum, 32);
    l_run = l_run * corr + psum;
    m_run = m_new;
    #pragma unroll
    for (int c2 = 0; c2 < 8; ++c2)
      #pragma unroll
      for (int r = 0; r < 4; ++r) of[c2][r] *= corr;

    __syncthreads();
    #pragma unroll
    for (int t2 = 0; t2 < 2; ++t2)
      #pragma unroll
      for (int r = 0; r < 4; ++r)
        Ps[t2*16 + lh*4 + r][lr] = pb[t2*4 + r];
    __syncthreads();

    // P fragment for PV: lane holds P[j-slot][i = lr]
    short8 pf;
    #pragma unroll
    for (int j = 0; j < 8; ++j) pf[j] = (short)Ps[lh*8 + j][lr];

    // O += mfma(A=V, B=P): reg r holds O[c = c2*16+lh*4+r][i = lr]
    #pragma unroll
    for (int c2 = 0; c2 < 8; ++c2) {
      short8 vf = *reinterpret_cast<const short8*>(&V[(size_t)(c2*16 + lr) * NPIX + kv0 + lh*8]);
      of[c2] = __builtin_amdgcn_mfma_f32_16x16x32_bf16(vf, pf, of[c2], 0, 0, 0);
    }
  }

  float inv = 1.f / l_run;
  #pragma unroll
  for (int c2 = 0; c2 < 8; ++c2)
    #pragma unroll
    for (int r = 0; r < 4; ++r) {
      int c = c2*16 + lh*4 + r;
      out[((size_t)b * CCH + h * HDIM + c) * NPIX + qt*16 + lr] = f2bf(of[c2][r] * inv);
    }
}

// ---------------- launch ----------------
extern "C" void kernel_launch(void* const* d_in, const int* in_sizes, int n_in,
                              void* d_out, int out_size, void* d_ws, size_t ws_size,
                              hipStream_t stream) {
  const float* x     = (const float*)d_in[0];
  const float* gamma = (const float*)d_in[1];
  const float* beta  = (const float*)d_in[2];
  const float* wqkv  = (const float*)d_in[3];
  const float* wproj = (const float*)d_in[4];
  const float* bproj = (const float*)d_in[5];
  float* out = (float*)d_out;

  char* ws = (char*)d_ws;
  // workspace layout (bytes)
  float* stats  = (float*)ws;                                   // 16*8*2*4 = 1 KB
  u16*   xn     = (u16*)(ws + 1024);                            // 16 MB
  u16*   wq_bf  = (u16*)(ws + 1024 + 16777216);                 // 1.5 MB
  u16*   wp_bf  = (u16*)(ws + 1024 + 16777216 + 1572864);       // 0.5 MB
  u16*   qkv    = (u16*)(ws + 1024 + 16777216 + 1572864 + 524288);            // 48 MB
  u16*   attno  = (u16*)(ws + 1024 + 16777216 + 1572864 + 524288 + 50331648); // 16 MB

  gn_stats_k<<<dim3(BATCH * NGRP), dim3(256), 0, stream>>>(x, stats);
  gn_apply_k<<<dim3(8192), dim3(256), 0, stream>>>(x, gamma, beta, stats, xn);
  f2bf_vec_k<<<dim3(768), dim3(256), 0, stream>>>(wqkv, wq_bf, 196608);
  f2bf_vec_k<<<dim3(256), dim3(256), 0, stream>>>(wproj, wp_bf, 65536);

  gemm_k512<false><<<dim3(16, 24, BATCH), dim3(256), 0, stream>>>(
      wq_bf, xn, qkv, nullptr, nullptr, nullptr);

  attn_k<<<dim3(64, NHEAD, BATCH), dim3(64), 0, stream>>>(qkv, attno);

  gemm_k512<true><<<dim3(16, 8, BATCH), dim3(256), 0, stream>>>(
      wp_bf, attno, nullptr, x, bproj, out);
}

// Round 2
// 369.687 us; speedup vs baseline: 2.2302x; 2.2302x over previous
//
#include <hip/hip_runtime.h>
#include <stdint.h>

typedef unsigned short u16;
typedef unsigned int u32;
typedef __attribute__((ext_vector_type(8))) short short8;
typedef __attribute__((ext_vector_type(4))) float f32x4;

#define BATCH 16
#define CCH   512
#define NPIX  1024
#define NGRP  8
#define CPG   64
#define NHEAD 4
#define HDIM  128
#define KVBLK 64

__device__ __forceinline__ u16 f2bf(float f) {
  union { float f; u32 u; } v; v.f = f;
  u32 u = v.u;
  u32 r = (u + 0x7FFFu + ((u >> 16) & 1u)) >> 16;
  return (u16)r;
}

// ---------------- GroupNorm stats: one block per (b,g) ----------------
__global__ void gn_stats_k(const float* __restrict__ x, float* __restrict__ stats) {
  int bg = blockIdx.x;
  const float* p = x + (size_t)bg * (CPG * NPIX);
  float s = 0.f, ss = 0.f;
  for (int i = threadIdx.x; i < (CPG * NPIX) / 4; i += 256) {
    float4 v = reinterpret_cast<const float4*>(p)[i];
    s  += v.x + v.y + v.z + v.w;
    ss += v.x*v.x + v.y*v.y + v.z*v.z + v.w*v.w;
  }
  for (int o = 32; o > 0; o >>= 1) { s += __shfl_down(s, o); ss += __shfl_down(ss, o); }
  __shared__ float sh[8];
  int wid = threadIdx.x >> 6;
  if ((threadIdx.x & 63) == 0) { sh[wid*2] = s; sh[wid*2+1] = ss; }
  __syncthreads();
  if (threadIdx.x == 0) {
    float ts  = sh[0]+sh[2]+sh[4]+sh[6];
    float tss = sh[1]+sh[3]+sh[5]+sh[7];
    const float inv = 1.f / (float)(CPG*NPIX);
    float mean = ts * inv;
    float var  = tss * inv - mean*mean;
    stats[bg*2]   = mean;
    stats[bg*2+1] = rsqrtf(var + 1e-5f);
  }
}

// ---------------- GroupNorm apply -> bf16 xn ----------------
__global__ void gn_apply_k(const float* __restrict__ x, const float* __restrict__ gamma,
                           const float* __restrict__ beta, const float* __restrict__ stats,
                           u16* __restrict__ xn) {
  int t = blockIdx.x * 256 + threadIdx.x;
  int c = (t >> 8) & (CCH - 1);
  int b = t >> 17;
  int g = c >> 6;
  float mean = stats[(b*NGRP + g)*2];
  float rstd = stats[(b*NGRP + g)*2 + 1];
  float ga = gamma[c] * rstd;
  float be = beta[c] - mean * ga;
  float4 v = reinterpret_cast<const float4*>(x)[t];
  u16 o0 = f2bf(v.x*ga + be), o1 = f2bf(v.y*ga + be);
  u16 o2 = f2bf(v.z*ga + be), o3 = f2bf(v.w*ga + be);
  u32 lo = (u32)o0 | ((u32)o1 << 16);
  u32 hi = (u32)o2 | ((u32)o3 << 16);
  reinterpret_cast<uint2*>(xn)[t] = make_uint2(lo, hi);
}

// ---------------- fp32 -> bf16 weight conversion ----------------
__global__ void f2bf_vec_k(const float* __restrict__ src, u16* __restrict__ dst, int n4) {
  int i = blockIdx.x * 256 + threadIdx.x;
  if (i >= n4) return;
  float4 v = reinterpret_cast<const float4*>(src)[i];
  u32 lo = (u32)f2bf(v.x) | ((u32)f2bf(v.y) << 16);
  u32 hi = (u32)f2bf(v.z) | ((u32)f2bf(v.w) << 16);
  reinterpret_cast<uint2*>(dst)[i] = make_uint2(lo, hi);
}

// ---------------- GEMM: C[b][m][n] = sum_k W[m][k] * Bm[b][k][n] ----------------
// PROJ=false: scatter C into Qt/Kt (token-major [bh][n][c]) and Vb ([bh][c][n]).
// PROJ=true:  outF = xres + C + bias[m] (fp32).
template <bool PROJ>
__global__ __launch_bounds__(256) void gemm_k512(const u16* __restrict__ W,
                                                 const u16* __restrict__ Bm,
                                                 u16* __restrict__ Qt,
                                                 u16* __restrict__ Kt,
                                                 u16* __restrict__ Vb,
                                                 const float* __restrict__ xres,
                                                 const float* __restrict__ bias,
                                                 float* __restrict__ outF) {
  const int b  = blockIdx.z;
  const int m0 = blockIdx.y * 64;
  const int n0 = blockIdx.x * 64;
  const u16* Bp = Bm + (size_t)b * CCH * NPIX;

  __shared__ u16 As[64][40];
  __shared__ u16 BsT[64][40];

  const int t    = threadIdx.x;
  const int lane = t & 63, wid = t >> 6;
  const int lr = lane & 15, lh = lane >> 4;
  const int wm = (wid >> 1) * 32, wn = (wid & 1) * 32;

  f32x4 acc[2][2] = {};

  const int ar = t >> 2, ac = (t & 3) * 8;
  const int br = t >> 3, bc = (t & 7) * 8;

  for (int kt = 0; kt < 16; ++kt) {
    const int k0 = kt * 32;
    *reinterpret_cast<uint4*>(&As[ar][ac]) =
        *reinterpret_cast<const uint4*>(&W[(size_t)(m0 + ar) * CCH + k0 + ac]);
    uint4 gv = *reinterpret_cast<const uint4*>(&Bp[(size_t)(k0 + br) * NPIX + n0 + bc]);
    u16 e[8];
    *reinterpret_cast<uint4*>(e) = gv;
    #pragma unroll
    for (int j = 0; j < 8; ++j) BsT[bc + j][br] = e[j];
    __syncthreads();

    short8 af[2], bfr[2];
    #pragma unroll
    for (int f = 0; f < 2; ++f)
      af[f] = *reinterpret_cast<const short8*>(&As[wm + f*16 + lr][lh*8]);
    #pragma unroll
    for (int f = 0; f < 2; ++f)
      bfr[f] = *reinterpret_cast<const short8*>(&BsT[wn + f*16 + lr][lh*8]);

    #pragma unroll
    for (int fm = 0; fm < 2; ++fm)
      #pragma unroll
      for (int fn = 0; fn < 2; ++fn)
        acc[fm][fn] = __builtin_amdgcn_mfma_f32_16x16x32_bf16(af[fm], bfr[fn], acc[fm][fn], 0, 0, 0);
    __syncthreads();
  }

  #pragma unroll
  for (int fm = 0; fm < 2; ++fm)
    #pragma unroll
    for (int fn = 0; fn < 2; ++fn)
      #pragma unroll
      for (int r = 0; r < 4; ++r) {
        int m = m0 + wm + fm*16 + lh*4 + r;
        int n = n0 + wn + fn*16 + lr;
        float v = acc[fm][fn][r];
        if (PROJ) {
          size_t off = ((size_t)b * CCH + m) * NPIX + n;
          outF[off] = xres[off] + v + bias[m];
        } else {
          u16 bv = f2bf(v);
          if (m < 512) {
            int hh = m >> 7, cc = m & 127;
            Qt[((size_t)(b*NHEAD + hh) * NPIX + n) * HDIM + cc] = bv;
          } else if (m < 1024) {
            int c = m - 512; int hh = c >> 7, cc = c & 127;
            Kt[((size_t)(b*NHEAD + hh) * NPIX + n) * HDIM + cc] = bv;
          } else {
            int c = m - 1024; int hh = c >> 7, cc = c & 127;
            Vb[((size_t)(b*NHEAD + hh) * HDIM + cc) * NPIX + n] = bv;
          }
        }
      }
}

// ---------------- Flash attention: 4 waves/block, 64 q rows, KV in LDS ----------------
// Qt,Kt token-major [bh][n][128]; Vb channel-major [bh][128][n]; out [b][512][n].
__global__ __launch_bounds__(256, 3) void attn_k(const u16* __restrict__ Qt,
                                                 const u16* __restrict__ Kt,
                                                 const u16* __restrict__ Vb,
                                                 u16* __restrict__ out) {
  // XCD-chunked bijective swizzle: grid 1024 = 8 XCDs * 128 consecutive ids.
  int id = blockIdx.x;
  int swz = (id & 7) * 128 + (id >> 3);
  const int qt = swz & 15;
  const int h  = (swz >> 4) & 3;
  const int b  = swz >> 6;
  const int bh = b * NHEAD + h;

  __shared__ u16 Ks[KVBLK * HDIM];      // [kv][c], XOR-swizzled, 16KB
  __shared__ u16 Vs[HDIM * KVBLK];      // [c][kv], XOR-swizzled, 16KB
  __shared__ u16 Ps[4][KVBLK][18];      // per-wave P

  const int t = threadIdx.x;
  const int lane = t & 63, w = t >> 6;
  const int lr = lane & 15, lh = lane >> 4;

  const u16*  Qb    = Qt + ((size_t)bh * NPIX + qt*64 + w*16) * HDIM;
  const char* Kbase = (const char*)Kt + (size_t)bh * (NPIX * HDIM * 2);
  const char* Vbase = (const char*)Vb + (size_t)bh * (NPIX * HDIM * 2);

  short8 qf[4];
  #pragma unroll
  for (int ct = 0; ct < 4; ++ct)
    qf[ct] = *reinterpret_cast<const short8*>(Qb + (size_t)lr * HDIM + ct*32 + lh*8);

  f32x4 of[8] = {};
  float m_run = -1e30f, l_run = 0.f;
  const float scale = 0.08838834764831845f;  // 1/sqrt(128)

  for (int kv0 = 0; kv0 < NPIX; kv0 += KVBLK) {
    // ---- load K/V tile to regs with pre-swizzled source (linear LDS dest) ----
    uint4 kreg[4], vreg[4];
    #pragma unroll
    for (int i = 0; i < 4; ++i) {
      int d = (i*256 + t) * 16;
      int kv = d >> 8;                              // 256B rows [kv][c]
      int srck = (d & ~255) | ((d & 255) ^ ((kv & 7) << 4));
      kreg[i] = *reinterpret_cast<const uint4*>(Kbase + kv0*256 + srck);
      int c = d >> 7;                               // 128B rows [c][kv]
      int srcv = (d & 127) ^ ((c & 7) << 4);
      vreg[i] = *reinterpret_cast<const uint4*>(Vbase + (size_t)c*2048 + kv0*2 + srcv);
    }
    __syncthreads();   // previous tile's compute done
    #pragma unroll
    for (int i = 0; i < 4; ++i) {
      int d = (i*256 + t) * 16;
      *reinterpret_cast<uint4*>((char*)Ks + d) = kreg[i];
      *reinterpret_cast<uint4*>((char*)Vs + d) = vreg[i];
    }
    __syncthreads();   // staging visible

    // ---- S = K Q^T over this 64-kv tile ----
    f32x4 s[4];
    #pragma unroll
    for (int t2 = 0; t2 < 4; ++t2) {
      f32x4 a = {};
      const int row = t2*16 + lr;
      #pragma unroll
      for (int ct = 0; ct < 4; ++ct) {
        const short8 kf = *reinterpret_cast<const short8*>(
            (const char*)Ks + row*256 + ((ct*64 + lh*16) ^ ((row & 7) << 4)));
        a = __builtin_amdgcn_mfma_f32_16x16x32_bf16(kf, qf[ct], a, 0, 0, 0);
      }
      s[t2] = a;
    }

    // ---- online softmax ----
    float sv[16];
    float tm = -1e30f;
    #pragma unroll
    for (int t2 = 0; t2 < 4; ++t2)
      #pragma unroll
      for (int r = 0; r < 4; ++r) {
        float xv = s[t2][r] * scale;
        sv[t2*4 + r] = xv;
        tm = fmaxf(tm, xv);
      }
    tm = fmaxf(tm, __shfl_xor(tm, 16));
    tm = fmaxf(tm, __shfl_xor(tm, 32));
    float m_new = fmaxf(m_run, tm);
    float corr = __expf(m_run - m_new);

    float psum = 0.f;
    u16 pb[16];
    #pragma unroll
    for (int i2 = 0; i2 < 16; ++i2) {
      float p = __expf(sv[i2] - m_new);
      psum += p;
      pb[i2] = f2bf(p);
    }
    psum += __shfl_xor(psum, 16);
    psum += __shfl_xor(psum, 32);
    l_run = l_run * corr + psum;
    m_run = m_new;
    #pragma unroll
    for (int c2 = 0; c2 < 8; ++c2)
      #pragma unroll
      for (int r = 0; r < 4; ++r) of[c2][r] *= corr;

    // ---- P through per-wave LDS (no cross-wave sync needed) ----
    #pragma unroll
    for (int t2 = 0; t2 < 4; ++t2)
      #pragma unroll
      for (int r = 0; r < 4; ++r)
        Ps[w][t2*16 + lh*4 + r][lr] = pb[t2*4 + r];

    // ---- O += V P ----
    #pragma unroll
    for (int ks = 0; ks < 2; ++ks) {
      short8 pf;
      #pragma unroll
      for (int j = 0; j < 8; ++j) pf[j] = (short)Ps[w][ks*32 + lh*8 + j][lr];
      #pragma unroll
      for (int c2 = 0; c2 < 8; ++c2) {
        const int c = c2*16 + lr;
        const short8 vf = *reinterpret_cast<const short8*>(
            (const char*)Vs + c*128 + ((ks*64 + lh*16) ^ ((c & 7) << 4)));
        of[c2] = __builtin_amdgcn_mfma_f32_16x16x32_bf16(vf, pf, of[c2], 0, 0, 0);
      }
    }
  }

  float inv = 1.f / l_run;
  #pragma unroll
  for (int c2 = 0; c2 < 8; ++c2)
    #pragma unroll
    for (int r = 0; r < 4; ++r) {
      int c = c2*16 + lh*4 + r;
      out[((size_t)b * CCH + h * HDIM + c) * NPIX + qt*64 + w*16 + lr] = f2bf(of[c2][r] * inv);
    }
}

// ---------------- launch ----------------
extern "C" void kernel_launch(void* const* d_in, const int* in_sizes, int n_in,
                              void* d_out, int out_size, void* d_ws, size_t ws_size,
                              hipStream_t stream) {
  const float* x     = (const float*)d_in[0];
  const float* gamma = (const float*)d_in[1];
  const float* beta  = (const float*)d_in[2];
  const float* wqkv  = (const float*)d_in[3];
  const float* wproj = (const float*)d_in[4];
  const float* bproj = (const float*)d_in[5];
  float* out = (float*)d_out;

  char* ws = (char*)d_ws;
  float* stats  = (float*)ws;                         // 1 KB
  u16*   xn     = (u16*)(ws + 1024);                  // 16 MB
  u16*   wq_bf  = (u16*)(ws + 1024 + (16u<<20));      // 1.5 MB
  u16*   wp_bf  = (u16*)(ws + 1024 + (16u<<20) + 1572864);
  u16*   Qt     = (u16*)(ws + 1024 + (16u<<20) + 1572864 + 524288);
  u16*   Kt     = (u16*)((char*)Qt + (16u<<20));
  u16*   Vb     = (u16*)((char*)Kt + (16u<<20));
  u16*   attno  = (u16*)((char*)Vb + (16u<<20));

  gn_stats_k<<<dim3(BATCH * NGRP), dim3(256), 0, stream>>>(x, stats);
  gn_apply_k<<<dim3(8192), dim3(256), 0, stream>>>(x, gamma, beta, stats, xn);
  f2bf_vec_k<<<dim3(768), dim3(256), 0, stream>>>(wqkv, wq_bf, 196608);
  f2bf_vec_k<<<dim3(256), dim3(256), 0, stream>>>(wproj, wp_bf, 65536);

  gemm_k512<false><<<dim3(16, 24, BATCH), dim3(256), 0, stream>>>(
      wq_bf, xn, Qt, Kt, Vb, nullptr, nullptr, nullptr);

  attn_k<<<dim3(1024), dim3(256), 0, stream>>>(Qt, Kt, Vb, attno);

  gemm_k512<true><<<dim3(16, 8, BATCH), dim3(256), 0, stream>>>(
      wp_bf, attno, nullptr, nullptr, nullptr, x, bproj, out);
}

// Round 3
// 174.351 us; speedup vs baseline: 4.7288x; 2.1204x over previous
//
#include <hip/hip_runtime.h>
#include <stdint.h>

typedef unsigned short u16;
typedef unsigned int u32;
typedef __attribute__((ext_vector_type(8))) short short8;
typedef __attribute__((ext_vector_type(4))) float f32x4;

#define BATCH 16
#define CCH   512
#define NPIX  1024
#define NGRP  8
#define CPG   64
#define NHEAD 4
#define HDIM  128
#define KVBLK 64

__device__ __forceinline__ u16 f2bf(float f) {
  union { float f; u32 u; } v; v.f = f;
  u32 u = v.u;
  u32 r = (u + 0x7FFFu + ((u >> 16) & 1u)) >> 16;
  return (u16)r;
}
__device__ __forceinline__ float bf2f(u16 b) {
  union { u32 u; float f; } v; v.u = ((u32)b) << 16; return v.f;
}

// async global->LDS, 16B per lane; dest = wave-uniform base + lane*16
__device__ __forceinline__ void gload16(const void* g, void* l) {
  typedef __attribute__((address_space(3))) u32 L;
  typedef __attribute__((address_space(1))) const u32 G;
  __builtin_amdgcn_global_load_lds((G*)(uintptr_t)g, (L*)(u32)(uintptr_t)l, 16, 0, 0);
}

// ---------------- GroupNorm stats: one block per (b,g) ----------------
__global__ void gn_stats_k(const float* __restrict__ x, float* __restrict__ stats) {
  int bg = blockIdx.x;
  const float* p = x + (size_t)bg * (CPG * NPIX);
  float s = 0.f, ss = 0.f;
  for (int i = threadIdx.x; i < (CPG * NPIX) / 4; i += 256) {
    float4 v = reinterpret_cast<const float4*>(p)[i];
    s  += v.x + v.y + v.z + v.w;
    ss += v.x*v.x + v.y*v.y + v.z*v.z + v.w*v.w;
  }
  for (int o = 32; o > 0; o >>= 1) { s += __shfl_down(s, o); ss += __shfl_down(ss, o); }
  __shared__ float sh[8];
  int wid = threadIdx.x >> 6;
  if ((threadIdx.x & 63) == 0) { sh[wid*2] = s; sh[wid*2+1] = ss; }
  __syncthreads();
  if (threadIdx.x == 0) {
    float ts  = sh[0]+sh[2]+sh[4]+sh[6];
    float tss = sh[1]+sh[3]+sh[5]+sh[7];
    const float inv = 1.f / (float)(CPG*NPIX);
    float mean = ts * inv;
    float var  = tss * inv - mean*mean;
    stats[bg*2]   = mean;
    stats[bg*2+1] = rsqrtf(var + 1e-5f);
  }
}

// ---------------- GroupNorm apply + transpose -> token-major bf16 xnT[tok][512] ----------------
__global__ __launch_bounds__(256) void gn_apply_t(const float* __restrict__ x,
                                                  const float* __restrict__ gamma,
                                                  const float* __restrict__ beta,
                                                  const float* __restrict__ stats,
                                                  u16* __restrict__ xnT) {
  const int p0 = blockIdx.x * 64;   // pixel tile
  const int c0 = blockIdx.y * 64;   // channel tile
  const int b  = blockIdx.z;
  __shared__ float lt[64][66];      // [pixloc][cloc], pitch 66 words

  const int t = threadIdx.x;
  #pragma unroll
  for (int pass = 0; pass < 4; ++pass) {
    int c   = c0 + (t >> 4) + pass * 16;
    int pix = p0 + (t & 15) * 4;
    int g = c >> 6;
    float mean = stats[(b*NGRP + g)*2];
    float rstd = stats[(b*NGRP + g)*2 + 1];
    float ga = gamma[c] * rstd;
    float be = beta[c] - mean * ga;
    float4 v = *reinterpret_cast<const float4*>(&x[((size_t)(b*CCH + c)) * NPIX + pix]);
    int pl = (t & 15) * 4, cl = (t >> 4) + pass * 16;
    lt[pl+0][cl] = v.x*ga + be;
    lt[pl+1][cl] = v.y*ga + be;
    lt[pl+2][cl] = v.z*ga + be;
    lt[pl+3][cl] = v.w*ga + be;
  }
  __syncthreads();
  const int pl = t >> 2, cq = (t & 3) * 16;
  u32 wbuf[8];
  #pragma unroll
  for (int e = 0; e < 8; ++e) {
    u16 lo = f2bf(lt[pl][cq + e*2]);
    u16 hi = f2bf(lt[pl][cq + e*2 + 1]);
    wbuf[e] = (u32)lo | ((u32)hi << 16);
  }
  u32* dst = (u32*)&xnT[((size_t)(b*NPIX + p0 + pl)) * CCH + c0 + cq];
  #pragma unroll
  for (int e = 0; e < 8; ++e) dst[e] = wbuf[e];
}

// ---------------- fp32 -> bf16 weight conversion ----------------
__global__ void f2bf_vec_k(const float* __restrict__ src, u16* __restrict__ dst, int n4) {
  int i = blockIdx.x * 256 + threadIdx.x;
  if (i >= n4) return;
  float4 v = reinterpret_cast<const float4*>(src)[i];
  u32 lo = (u32)f2bf(v.x) | ((u32)f2bf(v.y) << 16);
  u32 hi = (u32)f2bf(v.z) | ((u32)f2bf(v.w) << 16);
  reinterpret_cast<uint2*>(dst)[i] = make_uint2(lo, hi);
}

// ---------------- unified GEMM: D[ROW][COL] = sum_k Arows[ROW][k] * Brows[COL][k] ----------------
// MODE 0: ROW=token (xnT), COL=m (Wqk rows 0..1023)  -> Qt/Kt token-major [bh][pix][128]
// MODE 1: ROW=m (Wv), COL=token (xnT)               -> Vb channel-major [b*512+m][1024]
// MODE 2: ROW=m (Wproj), COL=token (attnO)          -> outF = xres + D + bias (fp32)
template <int MODE>
__global__ __launch_bounds__(256, 3) void gemm_t(const u16* __restrict__ Arows,
                                                 const u16* __restrict__ Brows,
                                                 u16* __restrict__ outQ,
                                                 u16* __restrict__ outK,
                                                 u16* __restrict__ outV,
                                                 const float* __restrict__ xres,
                                                 const float* __restrict__ bias,
                                                 float* __restrict__ outF) {
  __shared__ __align__(16) char smem[34816];   // A[16K] B[16K] / Dt 128*136*2

  const int id = blockIdx.x;
  const int NWG = (MODE == 0) ? 1024 : 512;
  const int wg = (id & 7) * (NWG >> 3) + (id >> 3);   // XCD-chunked, bijective (NWG%8==0)
  int rt, ct;
  if (MODE == 0) { rt = wg >> 3; ct = wg & 7; }
  else           { rt = wg & 3;  ct = wg >> 2; }

  const char* Ab = (const char*)Arows + (size_t)rt * 128 * 1024;  // row pitch 1024B (512 bf16)
  const char* Bb = (const char*)Brows + (size_t)ct * 128 * 1024;

  const int t = threadIdx.x;
  const int lane = t & 63, w = t >> 6;
  const int lr = lane & 15, lh = lane >> 4;
  const int rh = (w >> 1) * 64, ch = (w & 1) * 64;
  const int sw = (lr & 7) << 4;

  f32x4 acc[4][4] = {};

  for (int kt = 0; kt < 8; ++kt) {
    __syncthreads();
    #pragma unroll
    for (int i = 0; i < 4; ++i) {
      int d = w*4096 + i*1024 + lane*16;
      int row = d >> 7, colb = d & 127;
      int scol = colb ^ ((row & 7) << 4);
      gload16(Ab + (size_t)row*1024 + kt*128 + scol, smem + w*4096 + i*1024);
      gload16(Bb + (size_t)row*1024 + kt*128 + scol, smem + 16384 + w*4096 + i*1024);
    }
    __syncthreads();
    #pragma unroll
    for (int kk = 0; kk < 2; ++kk) {
      short8 a[4], bb[4];
      #pragma unroll
      for (int i = 0; i < 4; ++i) {
        int row = rh + i*16 + lr;
        a[i] = *reinterpret_cast<const short8*>(smem + row*128 + ((kk*64 + lh*16) ^ sw));
      }
      #pragma unroll
      for (int j = 0; j < 4; ++j) {
        int row = ch + j*16 + lr;
        bb[j] = *reinterpret_cast<const short8*>(smem + 16384 + row*128 + ((kk*64 + lh*16) ^ sw));
      }
      #pragma unroll
      for (int i = 0; i < 4; ++i)
        #pragma unroll
        for (int j = 0; j < 4; ++j)
          acc[i][j] = __builtin_amdgcn_mfma_f32_16x16x32_bf16(a[i], bb[j], acc[i][j], 0, 0, 0);
    }
  }

  if (MODE == 2) {
    const int m0 = rt * 128, tok0 = ct * 128;
    const int b = tok0 >> 10, pix0 = tok0 & 1023;
    #pragma unroll
    for (int i = 0; i < 4; ++i)
      #pragma unroll
      for (int j = 0; j < 4; ++j)
        #pragma unroll
        for (int r = 0; r < 4; ++r) {
          int m = m0 + rh + i*16 + lh*4 + r;
          int pix = pix0 + ch + j*16 + lr;
          size_t off = ((size_t)(b*CCH + m)) * NPIX + pix;
          outF[off] = xres[off] + acc[i][j][r] + bias[m];
        }
    return;
  }

  // MODE 0/1: LDS-transposed bf16 epilogue, 128B coalesced stores
  __syncthreads();
  u16* Dt = (u16*)smem;   // [128][136]
  #pragma unroll
  for (int i = 0; i < 4; ++i)
    #pragma unroll
    for (int j = 0; j < 4; ++j)
      #pragma unroll
      for (int r = 0; r < 4; ++r)
        Dt[(rh + i*16 + lh*4 + r) * 136 + ch + j*16 + lr] = f2bf(acc[i][j][r]);
  __syncthreads();

  const int rl = t >> 1, hoff = (t & 1) * 64;
  uint4 buf[8];
  const uint4* s4 = reinterpret_cast<const uint4*>(&Dt[rl*136 + hoff]);
  #pragma unroll
  for (int e = 0; e < 8; ++e) buf[e] = s4[e];

  u16* gdst;
  if (MODE == 0) {
    const int tok0 = rt * 128, m0 = ct * 128;
    const int b = tok0 >> 10, pix0 = tok0 & 1023;
    const int h = ct & 3;
    u16* base = (ct >= 4) ? outK : outQ;
    gdst = base + ((size_t)((b*NHEAD + h)) * NPIX + pix0 + rl) * HDIM + hoff;
  } else {
    const int m0 = rt * 128, tok0 = ct * 128;
    const int b = tok0 >> 10, pix0 = tok0 & 1023;
    gdst = outV + ((size_t)(b*CCH + m0 + rl)) * NPIX + pix0 + hoff;
  }
  uint4* g4 = reinterpret_cast<uint4*>(gdst);
  #pragma unroll
  for (int e = 0; e < 8; ++e) g4[e] = buf[e];
}

// ---------------- Flash attention: 4 waves/block, 64 q rows, gload_lds staging ----------------
// Qt,Kt token-major [bh][pix][128]; Vb channel-major [b*512+m][1024]; out attnO[tok][512].
__global__ __launch_bounds__(256, 3) void attn_k(const u16* __restrict__ Qt,
                                                 const u16* __restrict__ Kt,
                                                 const u16* __restrict__ Vb,
                                                 u16* __restrict__ attnO) {
  int id = blockIdx.x;
  int swz = (id & 7) * 128 + (id >> 3);
  const int qt = swz & 15;
  const int h  = (swz >> 4) & 3;
  const int b  = swz >> 6;
  const int bh = b * NHEAD + h;

  __shared__ __align__(16) char smem[41984];  // Ks 16K | Vs 16K | Ps 4*64*18*2
  char* KsB = smem;
  char* VsB = smem + 16384;

  const int t = threadIdx.x;
  const int lane = t & 63, w = t >> 6;
  const int lr = lane & 15, lh = lane >> 4;
  u16* Ps = (u16*)(smem + 32768) + w * (64 * 18);

  const u16*  Qb    = Qt + ((size_t)bh * NPIX + qt*64 + w*16) * HDIM;
  const char* Kbase = (const char*)(Kt + (size_t)bh * NPIX * HDIM);
  const char* Vbase = (const char*)(Vb + ((size_t)b*CCH + h*HDIM) * NPIX);

  const float scale = 0.08838834764831845f;  // 1/sqrt(128)
  short8 qf[4];
  #pragma unroll
  for (int ct = 0; ct < 4; ++ct) {
    short8 v = *reinterpret_cast<const short8*>(&Qb[(size_t)lr * HDIM + ct*32 + lh*8]);
    #pragma unroll
    for (int j = 0; j < 8; ++j) v[j] = (short)f2bf(bf2f((u16)v[j]) * scale);
    qf[ct] = v;
  }

  f32x4 of[8] = {};
  float m_run = -1e30f, l_run = 0.f;

  for (int kv0 = 0; kv0 < NPIX; kv0 += KVBLK) {
    __syncthreads();   // previous tile's LDS reads done
    #pragma unroll
    for (int i = 0; i < 4; ++i) {
      int d = w*4096 + i*1024 + lane*16;
      int krow = d >> 8, kcol = d & 255;
      gload16(Kbase + (size_t)(kv0 + krow)*256 + ((kcol & ~255) | (kcol ^ ((krow & 7) << 4))),
              KsB + w*4096 + i*1024);
      int vc = d >> 7, vcol = d & 127;
      gload16(Vbase + (size_t)vc*2048 + kv0*2 + (vcol ^ ((vc & 7) << 4)),
              VsB + w*4096 + i*1024);
    }
    __syncthreads();   // staging drained

    // ---- S = K Q^T (pre-scaled) ----
    f32x4 s[4];
    #pragma unroll
    for (int t2 = 0; t2 < 4; ++t2) {
      f32x4 a = {};
      const int row = t2*16 + lr;
      #pragma unroll
      for (int ct = 0; ct < 4; ++ct) {
        const short8 kf = *reinterpret_cast<const short8*>(
            KsB + row*256 + ((ct*64 + lh*16) ^ ((row & 7) << 4)));
        a = __builtin_amdgcn_mfma_f32_16x16x32_bf16(kf, qf[ct], a, 0, 0, 0);
      }
      s[t2] = a;
    }

    // ---- online softmax (fused) ----
    float tm = -1e30f;
    #pragma unroll
    for (int t2 = 0; t2 < 4; ++t2)
      #pragma unroll
      for (int r = 0; r < 4; ++r) tm = fmaxf(tm, s[t2][r]);
    tm = fmaxf(tm, __shfl_xor(tm, 16));
    tm = fmaxf(tm, __shfl_xor(tm, 32));
    float m_new = fmaxf(m_run, tm);
    float corr = __expf(m_run - m_new);

    float psum = 0.f;
    #pragma unroll
    for (int t2 = 0; t2 < 4; ++t2)
      #pragma unroll
      for (int r = 0; r < 4; ++r) {
        float p = __expf(s[t2][r] - m_new);
        psum += p;
        Ps[(t2*16 + lh*4 + r) * 18 + lr] = f2bf(p);
      }
    psum += __shfl_xor(psum, 16);
    psum += __shfl_xor(psum, 32);
    l_run = l_run * corr + psum;
    m_run = m_new;
    #pragma unroll
    for (int c2 = 0; c2 < 8; ++c2)
      #pragma unroll
      for (int r = 0; r < 4; ++r) of[c2][r] *= corr;

    // ---- O += V P ----
    #pragma unroll
    for (int ks = 0; ks < 2; ++ks) {
      short8 pf;
      #pragma unroll
      for (int j = 0; j < 8; ++j) pf[j] = (short)Ps[(ks*32 + lh*8 + j) * 18 + lr];
      #pragma unroll
      for (int c2 = 0; c2 < 8; ++c2) {
        const int c = c2*16 + lr;
        const short8 vf = *reinterpret_cast<const short8*>(
            VsB + c*128 + ((ks*64 + lh*16) ^ ((c & 7) << 4)));
        of[c2] = __builtin_amdgcn_mfma_f32_16x16x32_bf16(vf, pf, of[c2], 0, 0, 0);
      }
    }
  }

  // ---- epilogue: token-major, uint2 stores ----
  float inv = 1.f / l_run;
  const size_t rowbase = ((size_t)(b*NPIX + qt*64 + w*16 + lr)) * CCH + h*HDIM + lh*4;
  #pragma unroll
  for (int c2 = 0; c2 < 8; ++c2) {
    u32 lo = (u32)f2bf(of[c2][0]*inv) | ((u32)f2bf(of[c2][1]*inv) << 16);
    u32 hi = (u32)f2bf(of[c2][2]*inv) | ((u32)f2bf(of[c2][3]*inv) << 16);
    *reinterpret_cast<uint2*>(&attnO[rowbase + c2*16]) = make_uint2(lo, hi);
  }
}

// ---------------- launch ----------------
extern "C" void kernel_launch(void* const* d_in, const int* in_sizes, int n_in,
                              void* d_out, int out_size, void* d_ws, size_t ws_size,
                              hipStream_t stream) {
  const float* x     = (const float*)d_in[0];
  const float* gamma = (const float*)d_in[1];
  const float* beta  = (const float*)d_in[2];
  const float* wqkv  = (const float*)d_in[3];
  const float* wproj = (const float*)d_in[4];
  const float* bproj = (const float*)d_in[5];
  float* out = (float*)d_out;

  char* ws = (char*)d_ws;
  float* stats  = (float*)ws;                          // 1 KB
  u16*   xnT    = (u16*)(ws + 1024);                   // 16 MB  [16384][512]
  u16*   wq_bf  = (u16*)(ws + 1024 + (16u<<20));       // 1.5 MB [1536][512]
  u16*   wp_bf  = (u16*)((char*)wq_bf + 1572864);      // 0.5 MB
  u16*   Qt     = (u16*)((char*)wp_bf + 524288);       // 16 MB  [bh][1024][128]
  u16*   Kt     = (u16*)((char*)Qt + (16u<<20));       // 16 MB
  u16*   Vb     = (u16*)((char*)Kt + (16u<<20));       // 16 MB  [b*512+m][1024]
  u16*   attnO  = (u16*)((char*)Vb + (16u<<20));       // 16 MB  [16384][512]

  gn_stats_k<<<dim3(BATCH * NGRP), dim3(256), 0, stream>>>(x, stats);
  gn_apply_t<<<dim3(16, 8, BATCH), dim3(256), 0, stream>>>(x, gamma, beta, stats, xnT);
  f2bf_vec_k<<<dim3(768), dim3(256), 0, stream>>>(wqkv, wq_bf, 196608);
  f2bf_vec_k<<<dim3(256), dim3(256), 0, stream>>>(wproj, wp_bf, 65536);

  // QK projection: A=tokens, B=W rows 0..1023
  gemm_t<0><<<dim3(1024), dim3(256), 0, stream>>>(xnT, wq_bf, Qt, Kt, nullptr,
                                                  nullptr, nullptr, nullptr);
  // V projection: A=W rows 1024..1535, B=tokens
  gemm_t<1><<<dim3(512), dim3(256), 0, stream>>>(wq_bf + (size_t)1024*512, xnT,
                                                 nullptr, nullptr, Vb,
                                                 nullptr, nullptr, nullptr);

  attn_k<<<dim3(1024), dim3(256), 0, stream>>>(Qt, Kt, Vb, attnO);

  // proj: A=Wproj, B=attn tokens, fused residual+bias
  gemm_t<2><<<dim3(512), dim3(256), 0, stream>>>(wp_bf, attnO,
                                                 nullptr, nullptr, nullptr,
                                                 x, bproj, out);
}